// Round 9
// baseline (1582.237 us; speedup 1.0000x reference)
//
#include <hip/hip_runtime.h>

#define HH 128
#define TT 1024
#define NFUT 64
#define MB 2
#define NBLK 256
#define NITER (TT + NFUT)  // k=0..1087; iter k computes h1(k), h2(k-1)

typedef _Float16 half8 __attribute__((ext_vector_type(8)));
typedef float floatx4 __attribute__((ext_vector_type(4)));

#define MFMA16(a, b, c) __builtin_amdgcn_mfma_f32_16x16x32_f16((a), (b), (c), 0, 0, 0)

__device__ __forceinline__ float sigm(float v) {
  return __builtin_amdgcn_rcpf(1.0f + __builtin_amdgcn_exp2f(v * -1.442695040888963f));
}
__device__ __forceinline__ float tanh_f(float v) {
  float a = __builtin_fabsf(v);
  float e = __builtin_amdgcn_exp2f(a * -2.885390081777927f);
  float r = (1.0f - e) * __builtin_amdgcn_rcpf(1.0f + e);
  return __builtin_copysignf(r, v);
}
__device__ __forceinline__ half8 ldw8(const float* __restrict__ p) {
  half8 r;
#pragma unroll
  for (int i = 0; i < 8; ++i) r[i] = (_Float16)p[i];
  return r;
}

// Persistent 2-layer LSTM, 256 WG x 512 thr (8 waves), MB=2 rows/WG.
// SOFTWARE-PIPELINED: iter k computes h1(k) AND h2(k-1). All MFMA inputs are
// prev-iter buffers (h1(k-1), h2(k-2) = both in [prv]) -> ONE barrier/iter.
// Region order: G2-burst -> cell2-finalize -> G1-burst -> cell1-finalize;
// the 2 waves/SIMD drift across the region so MFMA (one wave) overlaps
// transcendentals (other wave). Bursts SPLIT so the g-accs die (extracted to
// scalars) before a-accs are born -> peak regs == r8's (no r6 spill).
// Accs zero-init (AGPR residency — r8 lesson); bias/x added post-MFMA.
// Race audit: reads [prv] pre-barrier(k); writes [cur] pre-barrier(k);
// [cur]@k read at k+1 post-barrier(k) ok; [prv]@k vs write@k+1 separated by
// barrier(k). opart: w@cell2-fin(k), mid-barrier, r@x(k), end-barrier, next w.
// Guards: cell2 finalize only k>=1 (else c2 corrupt), cell1 only k<=1086.
__global__
__attribute__((amdgpu_flat_work_group_size(512, 512), amdgpu_waves_per_eu(2, 2)))
void lstm_kernel(
    const float* __restrict__ x,
    const float* __restrict__ W_ih1, const float* __restrict__ b_ih1,
    const float* __restrict__ W_hh1, const float* __restrict__ b_hh1,
    const float* __restrict__ W_ih2, const float* __restrict__ b_ih2,
    const float* __restrict__ W_hh2, const float* __restrict__ b_hh2,
    const float* __restrict__ W_out, const float* __restrict__ b_out,
    float* __restrict__ out)
{
  __shared__ __align__(16) _Float16 h1b[2][2048];  // A-frag order; rows>=MB stay 0
  __shared__ __align__(16) _Float16 h2b[2][2048];
  __shared__ float xs[TT * MB];                    // [t][b] f32
  __shared__ float opart[8 * MB];

  const int tid = (int)threadIdx.x;
  const int lane = tid & 63;
  const int w = tid >> 6;
  const int jl = lane & 15;
  const int rg = lane >> 4;
  const int j = w * 16 + jl;
  const int b0g = (int)blockIdx.x * MB;

  for (int idx = tid; idx < TT * MB; idx += 512) {
    int t = idx & (TT - 1);
    int bb = idx >> 10;
    xs[t * MB + bb] = x[(b0g + bb) * TT + t];
  }
  for (int idx = tid; idx < 2 * 2048; idx += 512) {
    h1b[idx >> 11][idx & 2047] = (_Float16)0.0f;
    h2b[idx >> 11][idx & 2047] = (_Float16)0.0f;
  }

  // ---- 48 named weight B-fragments: A=W_hh1, H=W_hh2, I=W_ih2 ----
  half8 A00, A01, A02, A03, A10, A11, A12, A13, A20, A21, A22, A23, A30, A31, A32, A33;
  half8 H00, H01, H02, H03, H10, H11, H12, H13, H20, H21, H22, H23, H30, H31, H32, H33;
  half8 I00, I01, I02, I03, I10, I11, I12, I13, I20, I21, I22, I23, I30, I31, I32, I33;
#define LDW(N, Q, P) do { \
    const float* _p = (P) + ((Q) * HH + j) * HH + rg * 8; \
    N##0 = ldw8(_p);      N##1 = ldw8(_p + 32); \
    N##2 = ldw8(_p + 64); N##3 = ldw8(_p + 96); } while (0)
  LDW(A0, 0, W_hh1); LDW(A1, 1, W_hh1); LDW(A2, 2, W_hh1); LDW(A3, 3, W_hh1);
  LDW(H0, 0, W_hh2); LDW(H1, 1, W_hh2); LDW(H2, 2, W_hh2); LDW(H3, 3, W_hh2);
  LDW(I0, 0, W_ih2); LDW(I1, 1, W_ih2); LDW(I2, 2, W_ih2); LDW(I3, 3, W_ih2);

  float bias1[4], bias2[4], wi1[4];
#pragma unroll
  for (int q = 0; q < 4; ++q) {
    bias1[q] = b_ih1[q * HH + j] + b_hh1[q * HH + j];
    bias2[q] = b_ih2[q * HH + j] + b_hh2[q * HH + j];
    wi1[q] = W_ih1[q * HH + j];
  }
  const float wo = W_out[j];
  const float bo = b_out[0];
  float c1a = 0.f, c1b = 0.f, c2a = 0.f, c2b = 0.f;  // lanes 0-15 meaningful

  __syncthreads();

  const int aoff = lane * 8;
  const int wb = ((j >> 5) << 9) + (((j >> 3) & 3) << 7) + (j & 7);

#define G2K(KF) do { \
    half8 bv = *(const half8*)(&h2b[prv][KF * 512 + aoff]); \
    g0 = MFMA16(bv, H0##KF, g0); g1 = MFMA16(bv, H1##KF, g1); \
    g2 = MFMA16(bv, H2##KF, g2); g3 = MFMA16(bv, H3##KF, g3); \
    half8 aw = *(const half8*)(&h1b[prv][KF * 512 + aoff]); \
    g0 = MFMA16(aw, I0##KF, g0); g1 = MFMA16(aw, I1##KF, g1); \
    g2 = MFMA16(aw, I2##KF, g2); g3 = MFMA16(aw, I3##KF, g3); } while (0)
#define G1K(KF) do { \
    half8 av = *(const half8*)(&h1b[prv][KF * 512 + aoff]); \
    a0 = MFMA16(av, A0##KF, a0); a1 = MFMA16(av, A1##KF, a1); \
    a2 = MFMA16(av, A2##KF, a2); a3 = MFMA16(av, A3##KF, a3); } while (0)

  for (int k = 0; k < NITER; ++k) {
    const int cur = k & 1;
    const int prv = cur ^ 1;

    // ---- cell2 MFMA burst: gates2(k-1) = h2(k-2)@W_hh2^T + h1(k-1)@W_ih2^T ----
    floatx4 g0 = {0.f,0.f,0.f,0.f}, g1 = {0.f,0.f,0.f,0.f};
    floatx4 g2 = {0.f,0.f,0.f,0.f}, g3 = {0.f,0.f,0.f,0.f};
    __builtin_amdgcn_s_setprio(1);
    G2K(0); G2K(1); G2K(2); G2K(3);
    __builtin_amdgcn_s_setprio(0);

    // ---- cell2 finalize -> h2(k-1) ----
    if (k >= 1) {
      float gi0 = g0[0] + bias2[0], gi1 = g0[1] + bias2[0];
      float gf0 = g1[0] + bias2[1], gf1 = g1[1] + bias2[1];
      float gg0 = g2[0] + bias2[2], gg1 = g2[1] + bias2[2];
      float go0 = g3[0] + bias2[3], go1 = g3[1] + bias2[3];
      c2a = sigm(gf0) * c2a + sigm(gi0) * tanh_f(gg0);
      c2b = sigm(gf1) * c2b + sigm(gi1) * tanh_f(gg1);
      float h20 = sigm(go0) * tanh_f(c2a);
      float h21 = sigm(go1) * tanh_f(c2b);
      if (lane < 16) {
        h2b[cur][wb] = (_Float16)h20;
        h2b[cur][wb + 8] = (_Float16)h21;
      }
      if (k >= TT) {
        // projection partials over this wave's 16 units (xor closed in 0-15)
        float p0 = h20 * wo, p1 = h21 * wo;
        p0 += __shfl_xor(p0, 1); p1 += __shfl_xor(p1, 1);
        p0 += __shfl_xor(p0, 2); p1 += __shfl_xor(p1, 2);
        p0 += __shfl_xor(p0, 4); p1 += __shfl_xor(p1, 4);
        p0 += __shfl_xor(p0, 8); p1 += __shfl_xor(p1, 8);
        if (lane == 0) {
          opart[w * MB + 0] = p0;
          opart[w * MB + 1] = p1;
        }
      }
    }

    // ---- cell1 MFMA burst: gates1(k) = h1(k-1)@W_hh1^T ----
    floatx4 a0 = {0.f,0.f,0.f,0.f}, a1 = {0.f,0.f,0.f,0.f};
    floatx4 a2 = {0.f,0.f,0.f,0.f}, a3 = {0.f,0.f,0.f,0.f};
    __builtin_amdgcn_s_setprio(1);
    G1K(0); G1K(1); G1K(2); G1K(3);
    __builtin_amdgcn_s_setprio(0);

    // ---- x input for step k ----
    float x0, x1;
    if (k < TT) {
      x0 = xs[k * MB + 0];
      x1 = xs[k * MB + 1];
    } else {
      __syncthreads();  // publish opart: out(k-1) feedback
      float s0 = bo, s1 = bo;
#pragma unroll
      for (int p = 0; p < 8; ++p) {
        s0 += opart[p * MB + 0];
        s1 += opart[p * MB + 1];
      }
      x0 = s0; x1 = s1;
      if (w == 0 && lane < MB) out[(b0g + lane) * NFUT + (k - TT)] = (lane == 0) ? s0 : s1;
    }

    // ---- cell1 finalize -> h1(k) ----
    if (k <= NITER - 2) {
      float gi0 = a0[0] + x0 * wi1[0] + bias1[0], gi1 = a0[1] + x1 * wi1[0] + bias1[0];
      float gf0 = a1[0] + x0 * wi1[1] + bias1[1], gf1 = a1[1] + x1 * wi1[1] + bias1[1];
      float gg0 = a2[0] + x0 * wi1[2] + bias1[2], gg1 = a2[1] + x1 * wi1[2] + bias1[2];
      float go0 = a3[0] + x0 * wi1[3] + bias1[3], go1 = a3[1] + x1 * wi1[3] + bias1[3];
      c1a = sigm(gf0) * c1a + sigm(gi0) * tanh_f(gg0);
      c1b = sigm(gf1) * c1b + sigm(gi1) * tanh_f(gg1);
      float h10 = sigm(go0) * tanh_f(c1a);
      float h11 = sigm(go1) * tanh_f(c1b);
      if (lane < 16) {
        h1b[cur][wb] = (_Float16)h10;
        h1b[cur][wb + 8] = (_Float16)h11;
      }
    }
    __syncthreads();  // the ONE barrier: publish h1(k), h2(k-1)
    __builtin_amdgcn_sched_barrier(0);
  }
}

extern "C" void kernel_launch(void* const* d_in, const int* in_sizes, int n_in,
                              void* d_out, int out_size, void* d_ws, size_t ws_size,
                              hipStream_t stream) {
  const float* x     = (const float*)d_in[0];
  const float* W_ih1 = (const float*)d_in[1];
  const float* b_ih1 = (const float*)d_in[2];
  const float* W_hh1 = (const float*)d_in[3];
  const float* b_hh1 = (const float*)d_in[4];
  const float* W_ih2 = (const float*)d_in[5];
  const float* b_ih2 = (const float*)d_in[6];
  const float* W_hh2 = (const float*)d_in[7];
  const float* b_hh2 = (const float*)d_in[8];
  const float* W_out = (const float*)d_in[9];
  const float* b_out = (const float*)d_in[10];
  (void)in_sizes; (void)n_in; (void)out_size; (void)d_ws; (void)ws_size;

  lstm_kernel<<<dim3(NBLK), dim3(512), 0, stream>>>(
      x, W_ih1, b_ih1, W_hh1, b_hh1, W_ih2, b_ih2, W_hh2, b_hh2, W_out, b_out,
      (float*)d_out);
}

// Round 10
// 1488.668 us; speedup vs baseline: 1.0629x; 1.0629x over previous
//
#include <hip/hip_runtime.h>

#define HH 128
#define TT 1024
#define NFUT 64
#define MB 2
#define NBLK 256
#define NITER (TT + NFUT)  // k=0..1087; iter k computes h1(k), h2(k-1)

typedef _Float16 half8 __attribute__((ext_vector_type(8)));
typedef float floatx4 __attribute__((ext_vector_type(4)));

#define MFMA16(a, b, c) __builtin_amdgcn_mfma_f32_16x16x32_f16((a), (b), (c), 0, 0, 0)
#define SFENCE() __builtin_amdgcn_sched_barrier(0)

__device__ __forceinline__ float sigm(float v) {
  return __builtin_amdgcn_rcpf(1.0f + __builtin_amdgcn_exp2f(v * -1.442695040888963f));
}
__device__ __forceinline__ float tanh_f(float v) {
  float a = __builtin_fabsf(v);
  float e = __builtin_amdgcn_exp2f(a * -2.885390081777927f);
  float r = (1.0f - e) * __builtin_amdgcn_rcpf(1.0f + e);
  return __builtin_copysignf(r, v);
}
__device__ __forceinline__ half8 ldw8(const float* __restrict__ p) {
  half8 r;
#pragma unroll
  for (int i = 0; i < 8; ++i) r[i] = (_Float16)p[i];
  return r;
}

// Persistent 2-layer LSTM, 256 WG x 512 thr (8 waves), MB=2 rows/WG.
// SOFTWARE-PIPELINED: iter k computes h1(k) AND h2(k-1); all MFMA inputs are
// prev-iter buffers -> ONE s_barrier/iter (cross-wave drift = MFMA/VALU
// overlap across waves).
// SPILL DISCIPLINE (r6/r8/r9 lessons):
//  - accs zero-init (AGPR residency); bias/x added post-MFMA to scalars
//  - sched_barrier(0) at EVERY phase seam: without it the scheduler hoists
//    the next MFMA burst into the previous finalize -> both 16-reg acc sets
//    co-live -> >256 regs -> 95 MB scratch (r9). These fences are per-wave
//    compile-time only; they do NOT stop cross-wave overlap.
// Race audit: reads [prv] + writes [cur] both pre-barrier(k); [cur]@k first
// read post-barrier(k) at k+1; opart w@fin2(k), mid-barrier (future only),
// r@x(k), end-barrier before next write.
__global__
__attribute__((amdgpu_flat_work_group_size(512, 512), amdgpu_waves_per_eu(2, 2)))
void lstm_kernel(
    const float* __restrict__ x,
    const float* __restrict__ W_ih1, const float* __restrict__ b_ih1,
    const float* __restrict__ W_hh1, const float* __restrict__ b_hh1,
    const float* __restrict__ W_ih2, const float* __restrict__ b_ih2,
    const float* __restrict__ W_hh2, const float* __restrict__ b_hh2,
    const float* __restrict__ W_out, const float* __restrict__ b_out,
    float* __restrict__ out)
{
  __shared__ __align__(16) _Float16 h1b[2][2048];  // A-frag order; rows>=MB stay 0
  __shared__ __align__(16) _Float16 h2b[2][2048];
  __shared__ float xs[TT * MB];                    // [t][b] f32
  __shared__ float opart[8 * MB];

  const int tid = (int)threadIdx.x;
  const int lane = tid & 63;
  const int w = tid >> 6;
  const int jl = lane & 15;
  const int rg = lane >> 4;
  const int j = w * 16 + jl;
  const int b0g = (int)blockIdx.x * MB;

  for (int idx = tid; idx < TT * MB; idx += 512) {
    int t = idx & (TT - 1);
    int bb = idx >> 10;
    xs[t * MB + bb] = x[(b0g + bb) * TT + t];
  }
  for (int idx = tid; idx < 2 * 2048; idx += 512) {
    h1b[idx >> 11][idx & 2047] = (_Float16)0.0f;
    h2b[idx >> 11][idx & 2047] = (_Float16)0.0f;
  }

  // ---- 48 named weight B-fragments: A=W_hh1, H=W_hh2, I=W_ih2 ----
  half8 A00, A01, A02, A03, A10, A11, A12, A13, A20, A21, A22, A23, A30, A31, A32, A33;
  half8 H00, H01, H02, H03, H10, H11, H12, H13, H20, H21, H22, H23, H30, H31, H32, H33;
  half8 I00, I01, I02, I03, I10, I11, I12, I13, I20, I21, I22, I23, I30, I31, I32, I33;
#define LDW(N, Q, P) do { \
    const float* _p = (P) + ((Q) * HH + j) * HH + rg * 8; \
    N##0 = ldw8(_p);      N##1 = ldw8(_p + 32); \
    N##2 = ldw8(_p + 64); N##3 = ldw8(_p + 96); } while (0)
  LDW(A0, 0, W_hh1); LDW(A1, 1, W_hh1); LDW(A2, 2, W_hh1); LDW(A3, 3, W_hh1);
  LDW(H0, 0, W_hh2); LDW(H1, 1, W_hh2); LDW(H2, 2, W_hh2); LDW(H3, 3, W_hh2);
  LDW(I0, 0, W_ih2); LDW(I1, 1, W_ih2); LDW(I2, 2, W_ih2); LDW(I3, 3, W_ih2);

  float bias1[4], bias2[4], wi1[4];
#pragma unroll
  for (int q = 0; q < 4; ++q) {
    bias1[q] = b_ih1[q * HH + j] + b_hh1[q * HH + j];
    bias2[q] = b_ih2[q * HH + j] + b_hh2[q * HH + j];
    wi1[q] = W_ih1[q * HH + j];
  }
  const float wo = W_out[j];
  const float bo = b_out[0];
  float c1a = 0.f, c1b = 0.f, c2a = 0.f, c2b = 0.f;  // lanes 0-15 meaningful

  __syncthreads();

  const int aoff = lane * 8;
  const int wb = ((j >> 5) << 9) + (((j >> 3) & 3) << 7) + (j & 7);

#define G2K(KF) do { \
    half8 bv = *(const half8*)(&h2b[prv][KF * 512 + aoff]); \
    g0 = MFMA16(bv, H0##KF, g0); g1 = MFMA16(bv, H1##KF, g1); \
    g2 = MFMA16(bv, H2##KF, g2); g3 = MFMA16(bv, H3##KF, g3); \
    half8 aw = *(const half8*)(&h1b[prv][KF * 512 + aoff]); \
    g0 = MFMA16(aw, I0##KF, g0); g1 = MFMA16(aw, I1##KF, g1); \
    g2 = MFMA16(aw, I2##KF, g2); g3 = MFMA16(aw, I3##KF, g3); } while (0)
#define G1K(KF) do { \
    half8 av = *(const half8*)(&h1b[prv][KF * 512 + aoff]); \
    a0 = MFMA16(av, A0##KF, a0); a1 = MFMA16(av, A1##KF, a1); \
    a2 = MFMA16(av, A2##KF, a2); a3 = MFMA16(av, A3##KF, a3); } while (0)

  for (int k = 0; k < NITER; ++k) {
    const int cur = k & 1;
    const int prv = cur ^ 1;

    // ---- cell2 MFMA burst: gates2(k-1) = h2(k-2)@W_hh2^T + h1(k-1)@W_ih2^T ----
    floatx4 g0 = {0.f,0.f,0.f,0.f}, g1 = {0.f,0.f,0.f,0.f};
    floatx4 g2 = {0.f,0.f,0.f,0.f}, g3 = {0.f,0.f,0.f,0.f};
    __builtin_amdgcn_s_setprio(1);
    G2K(0); G2K(1); G2K(2); G2K(3);
    __builtin_amdgcn_s_setprio(0);
    SFENCE();  // g-accs extracted below; nothing from later phases moves up

    // ---- cell2 finalize -> h2(k-1) ----
    if (k >= 1) {
      float gi0 = g0[0] + bias2[0], gi1 = g0[1] + bias2[0];
      float gf0 = g1[0] + bias2[1], gf1 = g1[1] + bias2[1];
      float gg0 = g2[0] + bias2[2], gg1 = g2[1] + bias2[2];
      float go0 = g3[0] + bias2[3], go1 = g3[1] + bias2[3];
      c2a = sigm(gf0) * c2a + sigm(gi0) * tanh_f(gg0);
      c2b = sigm(gf1) * c2b + sigm(gi1) * tanh_f(gg1);
      float h20 = sigm(go0) * tanh_f(c2a);
      float h21 = sigm(go1) * tanh_f(c2b);
      if (lane < 16) {
        h2b[cur][wb] = (_Float16)h20;
        h2b[cur][wb + 8] = (_Float16)h21;
      }
      if (k >= TT) {
        float p0 = h20 * wo, p1 = h21 * wo;
        p0 += __shfl_xor(p0, 1); p1 += __shfl_xor(p1, 1);
        p0 += __shfl_xor(p0, 2); p1 += __shfl_xor(p1, 2);
        p0 += __shfl_xor(p0, 4); p1 += __shfl_xor(p1, 4);
        p0 += __shfl_xor(p0, 8); p1 += __shfl_xor(p1, 8);
        if (lane == 0) {
          opart[w * MB + 0] = p0;
          opart[w * MB + 1] = p1;
        }
      }
    }
    SFENCE();  // THE critical seam: G1 burst must not hoist into finalize2
               // (that co-lives both acc sets -> spill, r9's 95 MB WRITE)

    // ---- cell1 MFMA burst: gates1(k) = h1(k-1)@W_hh1^T ----
    floatx4 a0 = {0.f,0.f,0.f,0.f}, a1 = {0.f,0.f,0.f,0.f};
    floatx4 a2 = {0.f,0.f,0.f,0.f}, a3 = {0.f,0.f,0.f,0.f};
    __builtin_amdgcn_s_setprio(1);
    G1K(0); G1K(1); G1K(2); G1K(3);
    __builtin_amdgcn_s_setprio(0);
    SFENCE();

    // ---- x input for step k ----
    float x0, x1;
    if (k < TT) {
      x0 = xs[k * MB + 0];
      x1 = xs[k * MB + 1];
    } else {
      __syncthreads();  // publish opart: out(k-1) feedback
      float s0 = bo, s1 = bo;
#pragma unroll
      for (int p = 0; p < 8; ++p) {
        s0 += opart[p * MB + 0];
        s1 += opart[p * MB + 1];
      }
      x0 = s0; x1 = s1;
      if (w == 0 && lane < MB) out[(b0g + lane) * NFUT + (k - TT)] = (lane == 0) ? s0 : s1;
    }

    // ---- cell1 finalize -> h1(k) ----
    if (k <= NITER - 2) {
      float gi0 = a0[0] + x0 * wi1[0] + bias1[0], gi1 = a0[1] + x1 * wi1[0] + bias1[0];
      float gf0 = a1[0] + x0 * wi1[1] + bias1[1], gf1 = a1[1] + x1 * wi1[1] + bias1[1];
      float gg0 = a2[0] + x0 * wi1[2] + bias1[2], gg1 = a2[1] + x1 * wi1[2] + bias1[2];
      float go0 = a3[0] + x0 * wi1[3] + bias1[3], go1 = a3[1] + x1 * wi1[3] + bias1[3];
      c1a = sigm(gf0) * c1a + sigm(gi0) * tanh_f(gg0);
      c1b = sigm(gf1) * c1b + sigm(gi1) * tanh_f(gg1);
      float h10 = sigm(go0) * tanh_f(c1a);
      float h11 = sigm(go1) * tanh_f(c1b);
      if (lane < 16) {
        h1b[cur][wb] = (_Float16)h10;
        h1b[cur][wb + 8] = (_Float16)h11;
      }
    }
    __syncthreads();  // the ONE barrier: publish h1(k), h2(k-1)
    SFENCE();
  }
}

extern "C" void kernel_launch(void* const* d_in, const int* in_sizes, int n_in,
                              void* d_out, int out_size, void* d_ws, size_t ws_size,
                              hipStream_t stream) {
  const float* x     = (const float*)d_in[0];
  const float* W_ih1 = (const float*)d_in[1];
  const float* b_ih1 = (const float*)d_in[2];
  const float* W_hh1 = (const float*)d_in[3];
  const float* b_hh1 = (const float*)d_in[4];
  const float* W_ih2 = (const float*)d_in[5];
  const float* b_ih2 = (const float*)d_in[6];
  const float* W_hh2 = (const float*)d_in[7];
  const float* b_hh2 = (const float*)d_in[8];
  const float* W_out = (const float*)d_in[9];
  const float* b_out = (const float*)d_in[10];
  (void)in_sizes; (void)n_in; (void)out_size; (void)d_ws; (void)ws_size;

  lstm_kernel<<<dim3(NBLK), dim3(512), 0, stream>>>(
      x, W_ih1, b_ih1, W_hh1, b_hh1, W_ih2, b_ih2, W_hh2, b_hh2, W_out, b_out,
      (float*)d_out);
}